// Round 1
// baseline (56.048 us; speedup 1.0000x reference)
//
#include <hip/hip_runtime.h>

// Peg-solitaire batched env step. n = 262144 envs.
// Inputs (setup_inputs order):
//  0 pegs         float32 (n,33)
//  1 n_pegs       int32   (n)
//  2 done         bool    (n)      -- all false in test; read as bytes
//  3 total_reward float32 (n)
//  4 actions      int32   (n)
//  5 action_pos_ids      int32 (132)
//  6 action_mid_indices  int32 (132)
//  7 action_target_indices int32 (132)
//  8 oob_mask     bool (132)       -- UNUSED (recomputed from geometry)
//  9 i_indices    int32 (33)
// 10 j_indices    int32 (33)
// Output (flat float32, 184n):
//  rewards [0,n) | states [n,148n) (n,7,7,3) | done [148n,149n)
//  | pegs [149n,182n) | n_pegs [182n,183n) | total_reward [183n,184n)

#define EPB 64    // envs per block
#define NTH 256

__device__ __forceinline__ bool inboard(int i, int j) {
    return (i >= 0) && (i < 7) && (j >= 0) && (j < 7) &&
           (((i >= 2) && (i <= 4)) || ((j >= 2) && (j <= 4)));
}

__global__ __launch_bounds__(NTH) void peg_step(
    const float* __restrict__ pegs_in,
    const int* __restrict__ n_pegs_in,
    const unsigned char* __restrict__ done_in,
    const float* __restrict__ tot_rew_in,
    const int* __restrict__ actions,
    const int* __restrict__ pos_ids,
    const int* __restrict__ mid_idx,
    const int* __restrict__ tgt_idx,
    const int* __restrict__ i_ind,
    const int* __restrict__ j_ind,
    float* __restrict__ out,
    int n)
{
    __shared__ __align__(16) float s_pegs[EPB * 33];   // 2112 floats
    __shared__ int s_pos[132], s_mid[132], s_tgt[132], s_ok[132];
    __shared__ int s_rc2cell[49];
    __shared__ int s_ii[33], s_jj[33];
    __shared__ float s_r1[EPB], s_r2[EPB];
    __shared__ int s_f[4][EPB];

    const int t  = threadIdx.x;
    const int e0 = blockIdx.x * EPB;

    // ---- Phase 1: init inverse map, load grid coords, stage pegs (coalesced f4)
    if (t < 49) s_rc2cell[t] = -1;
    if (t < 33) { s_ii[t] = i_ind[t]; s_jj[t] = j_ind[t]; }
    {
        const float4* src = (const float4*)(pegs_in + (size_t)e0 * 33);
        float4* dst = (float4*)s_pegs;
        #pragma unroll
        for (int i = t; i < (EPB * 33) / 4; i += NTH) dst[i] = src[i];
    }
    __syncthreads();

    // ---- Phase 2: scatter inverse map; load action tables; recompute OOB
    if (t < 33) s_rc2cell[s_ii[t] * 7 + s_jj[t]] = t;
    if (t < 132) {
        int p = pos_ids[t];
        s_pos[t] = p;
        s_mid[t] = mid_idx[t];
        s_tgt[t] = tgt_idx[t];
        int mv = t & 3;                                // move_ids = tile(arange(4))
        int di = (mv == 0) ? -1 : (mv == 1) ? 1 : 0;   // moves: [-1,0],[1,0],[0,-1],[0,1]
        int dj = (mv == 2) ? -1 : (mv == 3) ? 1 : 0;
        int si = s_ii[p], sj = s_jj[p];
        s_ok[t] = inboard(si + di, sj + dj) && inboard(si + 2 * di, sj + 2 * dj);
    }
    __syncthreads();

    // ---- Phase 3: per-env jump execution + scalar outputs (wave 0 only)
    int np_new = 0;
    float reward = 0.0f;
    bool done_old = false;
    if (t < EPB) {
        int e = e0 + t;
        int a = actions[e];
        int p = s_pos[a], m = s_mid[a], g = s_tgt[a];
        float* row = s_pegs + t * 33;
        // write order matters when indices alias (OOB actions default to 0)
        row[p] = 0.0f;
        row[m] = 0.0f;
        row[g] = 1.0f;
        np_new = n_pegs_in[e] - 1;
        reward = (np_new == 1) ? 1.0f : (1.0f / 31.0f);
        done_old = (done_in[e] != 0);
        float npf = (float)np_new;
        s_r1[t] = (npf - 1.0f) * (1.0f / 31.0f);    // peg_ratio
        s_r2[t] = (32.0f - npf) * (1.0f / 31.0f);   // removed_ratio
        out[e] = reward;                            // rewards
        out[(size_t)182 * n + e] = npf;             // n_pegs (as f32)
        out[(size_t)183 * n + e] = tot_rew_in[e] + reward;  // total_reward
    }
    __syncthreads();

    // ---- Phase 4: feasibility scan, 4 threads/env x 33 actions each.
    // LDS row base = (t&63)*33 -> banks (lane+c)%32, conflict-free.
    {
        int el  = t & 63;
        int sub = t >> 6;
        const float* row = s_pegs + el * 33;
        int any = 0;
        int kbase = sub * 33;
        for (int kk = 0; kk < 33; ++kk) {
            int k = kbase + kk;
            if (s_ok[k]) {
                int f = (row[s_pos[k]] != 0.0f) && (row[s_mid[k]] > 0.0f) &&
                        (row[s_tgt[k]] == 0.0f);
                any |= f;
            }
        }
        s_f[sub][el] = any;
    }
    __syncthreads();

    // ---- Phase 5: done output + bulk coalesced writes (pegs, states)
    if (t < EPB) {
        int anyf = s_f[0][t] | s_f[1][t] | s_f[2][t] | s_f[3][t];
        // feasible &= ~done_old, so done_old forces done_new = true
        bool dn = (np_new == 1) || done_old || (anyf == 0);
        out[(size_t)148 * n + (e0 + t)] = dn ? 1.0f : 0.0f;
    }
    {   // pegs out: 528 float4, coalesced
        const float4* src = (const float4*)s_pegs;
        float4* dst = (float4*)(out + (size_t)149 * n + (size_t)e0 * 33);
        #pragma unroll
        for (int i = t; i < (EPB * 33) / 4; i += NTH) dst[i] = src[i];
    }
    {   // states out: 64*147 floats = 2352 float4 per block, coalesced
        float4* dst = (float4*)(out + (size_t)n + (size_t)e0 * 147);
        for (int q = t; q < (EPB * 147) / 4; q += NTH) {
            int f   = q * 4;
            int env = f / 147;          // magic-mul (compile-time divisor)
            int el  = f - env * 147;
            float v[4];
            #pragma unroll
            for (int r = 0; r < 4; ++r) {
                int rc = el / 3;
                int ch = el - rc * 3;
                float x;
                if (ch == 0) {
                    int c = s_rc2cell[rc];
                    x = (c >= 0) ? s_pegs[env * 33 + c] : 0.0f;
                } else if (ch == 1) {
                    x = s_r1[env];
                } else {
                    x = s_r2[env];
                }
                v[r] = x;
                if (++el == 147) { el = 0; ++env; }
            }
            dst[q] = make_float4(v[0], v[1], v[2], v[3]);
        }
    }
}

extern "C" void kernel_launch(void* const* d_in, const int* in_sizes, int n_in,
                              void* d_out, int out_size, void* d_ws, size_t ws_size,
                              hipStream_t stream) {
    const float* pegs          = (const float*)d_in[0];
    const int* n_pegs          = (const int*)d_in[1];
    const unsigned char* done  = (const unsigned char*)d_in[2];
    const float* total_reward  = (const float*)d_in[3];
    const int* actions         = (const int*)d_in[4];
    const int* pos_ids         = (const int*)d_in[5];
    const int* mid_idx         = (const int*)d_in[6];
    const int* tgt_idx         = (const int*)d_in[7];
    // d_in[8] = oob_mask: unused (recomputed on-device from geometry)
    const int* i_ind           = (const int*)d_in[9];
    const int* j_ind           = (const int*)d_in[10];
    float* out = (float*)d_out;

    int n = in_sizes[1];            // 262144 (divisible by EPB=64)
    dim3 grid(n / EPB), block(NTH);
    hipLaunchKernelGGL(peg_step, grid, block, 0, stream,
                       pegs, n_pegs, done, total_reward, actions,
                       pos_ids, mid_idx, tgt_idx, i_ind, j_ind, out, n);
}

// Round 2
// 45.425 us; speedup vs baseline: 1.2339x; 1.2339x over previous
//
#include <hip/hip_runtime.h>

// Peg-solitaire batched env step, bitboard edition. n = 262144 envs.
// Inputs (setup_inputs order):
//  0 pegs float32 (n,33) | 1 n_pegs int32 (n) | 2 done bool (n)
//  3 total_reward f32 (n) | 4 actions int32 (n)
//  5 action_pos_ids (132) | 6 action_mid_indices (132) | 7 action_target_indices (132)
//  8 oob_mask (unused; geometry recomputed) | 9 i_indices (33) | 10 j_indices (33)
// Output flat f32 (184n): rewards[0,n) | states[n,148n) | done[148n,149n)
//  | pegs[149n,182n) | n_pegs[182n,183n) | total_reward[183n,184n)
//
// Feasibility via 49-bit bitboard in 7x7 coords (bit = i*7+j):
//   E = ~P & B;  feasible_d = P & shift(P,d) & shift(E,2d) [& colmask for d=±1]
// Column masks prevent row wraparound for horizontal moves; vertical shifts
// fall off the 49-bit board naturally (E,P subset of B, bits < 49).

#define EPB 256   // envs per block, one thread per env
#define NTH 256

constexpr unsigned long long cross_mask() {
    unsigned long long b = 0;
    for (int i = 0; i < 7; ++i)
        for (int j = 0; j < 7; ++j)
            if ((i >= 2 && i <= 4) || (j >= 2 && j <= 4))
                b |= 1ull << (i * 7 + j);
    return b;
}
constexpr unsigned long long cols_le(int jmax) {
    unsigned long long b = 0;
    for (int i = 0; i < 7; ++i)
        for (int j = 0; j <= jmax; ++j) b |= 1ull << (i * 7 + j);
    return b;
}
constexpr unsigned long long cols_ge(int jmin) {
    unsigned long long b = 0;
    for (int i = 0; i < 7; ++i)
        for (int j = jmin; j < 7; ++j) b |= 1ull << (i * 7 + j);
    return b;
}
constexpr unsigned long long B_MASK = cross_mask();
constexpr unsigned long long C_LE4  = cols_le(4);  // sources for j+1 jumps
constexpr unsigned long long C_GE2  = cols_ge(2);  // sources for j-1 jumps

__global__ __launch_bounds__(NTH) void peg_step(
    const float* __restrict__ pegs_in,
    const int* __restrict__ n_pegs_in,
    const unsigned char* __restrict__ done_in,
    const float* __restrict__ tot_rew_in,
    const int* __restrict__ actions,
    const int* __restrict__ pos_ids,
    const int* __restrict__ mid_idx,
    const int* __restrict__ tgt_idx,
    const int* __restrict__ i_ind,
    const int* __restrict__ j_ind,
    float* __restrict__ out,
    int n)
{
    __shared__ __align__(16) float s_pegs[EPB * 33];          // 33.8 KB
    __shared__ int s_pos[132], s_mid[132], s_tgt[132];
    __shared__ int s_c2b[33];                                  // cell -> i*7+j
    __shared__ unsigned long long s_bb[EPB];
    __shared__ float s_r1[EPB], s_r2[EPB];

    const int t  = threadIdx.x;
    const int e0 = blockIdx.x * EPB;
    const int e  = e0 + t;

    // ---- early per-env scalar loads (coalesced; overlap with staging)
    const int a        = actions[e];
    const int np_new   = n_pegs_in[e] - 1;
    const bool done_old = (done_in[e] != 0);
    const float tot    = tot_rew_in[e];

    if (t < 132) { s_pos[t] = pos_ids[t]; s_mid[t] = mid_idx[t]; s_tgt[t] = tgt_idx[t]; }
    if (t < 33)  s_c2b[t] = i_ind[t] * 7 + j_ind[t];

    // ---- stage pegs rows into LDS (coalesced float4)
    {
        const float4* src = (const float4*)(pegs_in + (size_t)e0 * 33);
        float4* dst = (float4*)s_pegs;
        #pragma unroll
        for (int i = t; i < EPB * 33 / 4; i += NTH) dst[i] = src[i];
    }
    __syncthreads();

    // ---- per-env: apply jump to own row (write order pos<-0, mid<-0, tgt<-1
    //      matters when OOB defaults alias), then build post-jump bitboard.
    float* row = s_pegs + t * 33;
    row[s_pos[a]] = 0.0f;
    row[s_mid[a]] = 0.0f;
    row[s_tgt[a]] = 1.0f;

    unsigned long long P = 0;
    #pragma unroll
    for (int c = 0; c < 33; ++c)
        P |= (unsigned long long)(row[c] != 0.0f) << s_c2b[c];

    // ---- feasibility over all 132 actions in ~15 wide ops
    const unsigned long long E = ~P & B_MASK;
    const unsigned long long feas =
        (P & (P >> 1) & (E >> 2)  & C_LE4) |   // j+1 jumps
        (P & (P << 1) & (E << 2)  & C_GE2) |   // j-1 jumps
        (P & (P >> 7) & (E >> 14))         |   // i+1 jumps
        (P & (P << 7) & (E << 14));            // i-1 jumps

    const float rw  = (np_new == 1) ? 1.0f : (1.0f / 31.0f);
    const bool  dn  = (np_new == 1) | done_old | (feas == 0ull);
    const float npf = (float)np_new;

    out[e]                    = rw;                    // rewards
    out[(size_t)148 * n + e]  = dn ? 1.0f : 0.0f;      // done
    out[(size_t)182 * n + e]  = npf;                   // n_pegs
    out[(size_t)183 * n + e]  = tot + rw;              // total_reward

    s_bb[t] = P;
    s_r1[t] = (npf - 1.0f)  * (1.0f / 31.0f);          // peg_ratio
    s_r2[t] = (32.0f - npf) * (1.0f / 31.0f);          // removed_ratio
    __syncthreads();

    // ---- pegs out: coalesced float4 from LDS
    {
        const float4* src = (const float4*)s_pegs;
        float4* dst = (float4*)(out + (size_t)149 * n + (size_t)e0 * 33);
        #pragma unroll
        for (int i = t; i < EPB * 33 / 4; i += NTH) dst[i] = src[i];
    }

    // ---- states out: (env,7,7,3); el = rc*3+ch; ch0 = bit rc of bb (rc==i*7+j),
    //      ch1/ch2 = ratios. Broadcast LDS reads only; values from registers.
    {
        float4* dst = (float4*)(out + (size_t)n + (size_t)e0 * 147);
        const int total = EPB * 147 / 4;               // 9408
        for (int q = t; q < total; q += NTH) {
            int f4  = q * 4;
            int env = f4 / 147;                        // magic-mul (const divisor)
            int el  = f4 - env * 147;
            unsigned long long bb = s_bb[env];
            float r1 = s_r1[env], r2 = s_r2[env];
            float v[4];
            #pragma unroll
            for (int r = 0; r < 4; ++r) {
                if (el == 147) {                       // env boundary (refresh before use)
                    el = 0; ++env;
                    bb = s_bb[env]; r1 = s_r1[env]; r2 = s_r2[env];
                }
                int rc = el / 3;
                int ch = el - rc * 3;
                float x = (ch == 0) ? (float)((unsigned int)(bb >> rc) & 1u)
                                    : ((ch == 1) ? r1 : r2);
                v[r] = x;
                ++el;
            }
            dst[q] = make_float4(v[0], v[1], v[2], v[3]);
        }
    }
}

extern "C" void kernel_launch(void* const* d_in, const int* in_sizes, int n_in,
                              void* d_out, int out_size, void* d_ws, size_t ws_size,
                              hipStream_t stream) {
    const float* pegs          = (const float*)d_in[0];
    const int* n_pegs          = (const int*)d_in[1];
    const unsigned char* done  = (const unsigned char*)d_in[2];
    const float* total_reward  = (const float*)d_in[3];
    const int* actions         = (const int*)d_in[4];
    const int* pos_ids         = (const int*)d_in[5];
    const int* mid_idx         = (const int*)d_in[6];
    const int* tgt_idx         = (const int*)d_in[7];
    // d_in[8] oob_mask: unused (recomputed from geometry)
    const int* i_ind           = (const int*)d_in[9];
    const int* j_ind           = (const int*)d_in[10];
    float* out = (float*)d_out;

    int n = in_sizes[1];                    // 262144, divisible by EPB
    dim3 grid(n / EPB), block(NTH);
    hipLaunchKernelGGL(peg_step, grid, block, 0, stream,
                       pegs, n_pegs, done, total_reward, actions,
                       pos_ids, mid_idx, tgt_idx, i_ind, j_ind, out, n);
}